// Round 13
// baseline (431.927 us; speedup 1.0000x reference)
//
#include <hip/hip_runtime.h>

#define NN 50000
#define EE 800000
#define GG 256
#define IND 32
#define HID 108
#define NL 4
#define MB 782            // ceil(50000/64) M-tiles (embed)
#define MB2 1563          // ceil(50000/32) M-tiles (appmm1, agg)
#define RS 8              // readout slices per graph
#define SBN 196           // super-buckets of 256 nodes (ceil(50000/256))
#define SCAP 5120         // ebuf slot capacity per super-bucket (mean 4082, sd 64 -> 16 sigma)
#define PCAP 6144         // k_place2 LDS staging capacity
#define PAD 16            // ints (64B) padding for atomic counters
#define BCH 4096          // edges per k_bin block
#define STL 136           // LDS tile row stride (halves): 272B -> 2-way (free) bank aliasing

typedef __attribute__((ext_vector_type(8))) _Float16 f16x8;
typedef __attribute__((ext_vector_type(4))) float floatx4;
typedef __attribute__((ext_vector_type(4))) unsigned int uintx4;

__global__ void k_zero(int* p, int n) {
    int i = blockIdx.x * 256 + threadIdx.x;
    if (i < n) p[i] = 0;
}

// ---- two-level coalesced CSR build ----
// level 1: bin edges by super-bucket (dst>>8) with LDS staging so global writes
// are contiguous runs per (block, super-bucket). payload = (sb<<24)|(src<<8)|(dst&255)
__global__ __launch_bounds__(256)
void k_bin(const int* __restrict__ src, const int* __restrict__ dst,
           int* __restrict__ gfill, unsigned int* __restrict__ ebuf) {
    __shared__ unsigned int stage[BCH];
    __shared__ int scnt[SBN], soff[SBN], gres[SBN];
    __shared__ int wsum[4], wexc[4];
    int tid = threadIdx.x;
    int e0 = blockIdx.x * BCH;
    for (int i = tid; i < SBN; i += 256) scnt[i] = 0;
    __syncthreads();
    unsigned int pay[16]; int psb[16];
    #pragma unroll
    for (int j = 0; j < 16; j++) {
        int e = e0 + j * 256 + tid;              // coalesced
        if (e < EE) {
            int d = dst[e]; int s = src[e];
            int sb = d >> 8;
            psb[j] = sb;
            pay[j] = ((unsigned)sb << 24) | ((unsigned)s << 8) | (unsigned)(d & 255);
            atomicAdd(&scnt[sb], 1);
        } else psb[j] = -1;
    }
    __syncthreads();
    // wave-parallel exclusive scan of scnt[0..SBN) -> soff
    {
        int lane = tid & 63, wv = tid >> 6;
        int v = (tid < SBN) ? scnt[tid] : 0;
        int x = v;
        #pragma unroll
        for (int o = 1; o < 64; o <<= 1) {
            int y = __shfl_up(x, o, 64);
            if (lane >= o) x += y;
        }
        if (lane == 63) wsum[wv] = x;
        __syncthreads();
        if (tid == 0) { int run = 0; for (int w = 0; w < 4; w++) { wexc[w] = run; run += wsum[w]; } }
        __syncthreads();
        if (tid < SBN) soff[tid] = wexc[wv] + x - v;
    }
    __syncthreads();
    if (tid < SBN) gres[tid] = atomicAdd(&gfill[tid * PAD], scnt[tid]);
    __syncthreads();
    if (tid < SBN) scnt[tid] = 0;
    __syncthreads();
    #pragma unroll
    for (int j = 0; j < 16; j++) {
        if (psb[j] >= 0) {
            int p = soff[psb[j]] + atomicAdd(&scnt[psb[j]], 1);
            stage[p] = pay[j];
        }
    }
    __syncthreads();
    int nv = soff[SBN - 1] + scnt[SBN - 1];
    for (int i = tid; i < nv; i += 256) {
        unsigned int v = stage[i];
        int sb = v >> 24;
        int idx = gres[sb] + (i - soff[sb]);
        if (idx < SCAP) ebuf[(size_t)sb * SCAP + idx] = v & 0xFFFFFFu;  // (src<<8)|loc
    }
}

// level 2: per super-bucket, build node-sorted CSR fully in LDS, coalesced writes.
// emits rp (256 nodes) and cs (ushort: src < 50000 < 2^16).
__global__ __launch_bounds__(256)
void k_place2(const unsigned int* __restrict__ ebuf, const int* __restrict__ gfill,
              int* __restrict__ rp, unsigned short* __restrict__ cs) {
    __shared__ int outb[PCAP];
    __shared__ int cnt[256];
    __shared__ int off[256];
    __shared__ int fl[SBN];
    __shared__ int sred[4];
    __shared__ int wsum[4], wexc[4];
    int sb = blockIdx.x, tid = threadIdx.x;
    if (tid < SBN) fl[tid] = gfill[tid * PAD];
    cnt[tid] = 0;
    __syncthreads();
    // parallel sum of fl[0..sb) -> sbase
    {
        int lane = tid & 63, wv = tid >> 6;
        int v = (tid < sb) ? fl[tid] : 0;
        #pragma unroll
        for (int o = 1; o < 64; o <<= 1) v += __shfl_xor(v, o, 64);
        if (lane == 0) sred[wv] = v;
    }
    __syncthreads();
    int base = sred[0] + sred[1] + sred[2] + sred[3];
    int nE = fl[sb]; if (nE > SCAP) nE = SCAP;
    const unsigned int* eb = ebuf + (size_t)sb * SCAP;
    for (int i = tid; i < nE; i += 256) atomicAdd(&cnt[eb[i] & 255], 1);
    __syncthreads();
    // exclusive scan of 256 counts
    int v = cnt[tid];
    int lane = tid & 63, wv = tid >> 6;
    int x = v;
    #pragma unroll
    for (int o = 1; o < 64; o <<= 1) {
        int y = __shfl_up(x, o, 64);
        if (lane >= o) x += y;
    }
    if (lane == 63) wsum[wv] = x;
    __syncthreads();
    if (tid == 0) { int run = 0; for (int w = 0; w < 4; w++) { wexc[w] = run; run += wsum[w]; } }
    __syncthreads();
    int myoff = wexc[wv] + x - v;
    off[tid] = myoff;
    int n = (sb << 8) + tid;
    if (n <= NN) rp[n] = base + myoff;
    cnt[tid] = 0;
    __syncthreads();
    if (nE <= PCAP) {
        for (int i = tid; i < nE; i += 256) {
            unsigned int e = eb[i];
            int loc = e & 255;
            int p = atomicAdd(&cnt[loc], 1);
            outb[off[loc] + p] = (int)(e >> 8);
        }
        __syncthreads();
        for (int i = tid; i < nE; i += 256) cs[base + i] = (unsigned short)outb[i];
    } else {
        for (int i = tid; i < nE; i += 256) {
            unsigned int e = eb[i];
            int loc = e & 255;
            int p = atomicAdd(&cnt[loc], 1);
            cs[base + off[loc] + p] = (unsigned short)(e >> 8);
        }
    }
}

// Pack weights (fp16, transposed, padded):
// Bt1[l][128][128]  : pool, n<108,k<108 -> W_pool[l][k][n]
// BtA[l][108][256]  : app,  row n<108; k<108 -> W_app[l][k][n]; 128<=k<236 -> W_app[l][108+k-128][n]
__global__ void k_pack(const float* __restrict__ W_pool, const float* __restrict__ b_pool,
                       const float* __restrict__ W_app, const float* __restrict__ b_app,
                       const float* __restrict__ W_emb, const float* __restrict__ b_emb,
                       _Float16* Bt1, _Float16* BtA, float* bbP, float* bbA,
                       _Float16* BtE, float* bbE) {
    int r = blockIdx.x * 256 + threadIdx.x;
    if (r < NL * 128 * 128) {
        int l = r / (128 * 128); int t = r % (128 * 128); int n = t / 128, k = t % 128;
        float v = (n < HID && k < HID) ? W_pool[((size_t)l * HID + k) * HID + n] : 0.f;
        Bt1[r] = (_Float16)v; return;
    } r -= NL * 128 * 128;
    if (r < NL * 108 * 256) {
        int l = r / (108 * 256); int t = r % (108 * 256); int n = t / 256, k = t % 256;
        float v = 0.f;
        if (k < HID)                        v = W_app[((size_t)l * 216 + k) * HID + n];
        else if (k >= 128 && k < 128 + HID) v = W_app[((size_t)l * 216 + 108 + (k - 128)) * HID + n];
        BtA[r] = (_Float16)v; return;
    } r -= NL * 108 * 256;
    if (r < NL * 128) { int l = r / 128, n = r % 128; bbP[r] = (n < HID) ? b_pool[l * HID + n] : 0.f; return; } r -= NL * 128;
    if (r < NL * 128) { int l = r / 128, n = r % 128; bbA[r] = (n < HID) ? b_app[l * HID + n] : 0.f; return; } r -= NL * 128;
    if (r < 128 * 32) {
        int n = r / 32, k = r % 32;
        BtE[r] = (n < HID) ? (_Float16)W_emb[k * HID + n] : (_Float16)0.f; return;
    } r -= 128 * 32;
    if (r < 128) { bbE[r] = (r < HID) ? b_emb[r] : 0.f; }
}

// embed via MFMA + fused mm1(layer 0):
// v = feat(fp16)[M,32] @ BtE^T + bias -> h16 (fp16 residual carrier); stage v in LDS;
// hp16 (slice-major [4][NN][32]) = relu(stage @ Bt1[0]^T + bbP[0])
__global__ __launch_bounds__(256)
void k_embed2(const float* __restrict__ feat, const _Float16* __restrict__ BtE,
              const float* __restrict__ bias,
              const _Float16* __restrict__ Bt1n, const float* __restrict__ bbPn,
              _Float16* __restrict__ h16, _Float16* __restrict__ hp16) {
    __shared__ _Float16 Bl[128 * 32];
    __shared__ _Float16 stg[64 * STL];
    int tid = threadIdx.x;
    for (int i = tid; i < 128 * 32 / 8; i += 256)
        ((uintx4*)Bl)[i] = ((const uintx4*)BtE)[i];
    __syncthreads();
    int lane = tid & 63, wid = tid >> 6, lm = lane & 15, lq = lane >> 4;
    int m0 = blockIdx.x * 64;
    floatx4 acc[4][2];
    #pragma unroll
    for (int mi = 0; mi < 4; mi++)
        #pragma unroll
        for (int ni = 0; ni < 2; ni++) { floatx4 z = {0.f,0.f,0.f,0.f}; acc[mi][ni] = z; }
    f16x8 a[4], b[2];
    #pragma unroll
    for (int mi = 0; mi < 4; mi++) {
        int row = m0 + mi * 16 + lm;
        f16x8 av;
        if (row < NN) {
            const float4 v0 = *(const float4*)(feat + (size_t)row * 32 + lq * 8);
            const float4 v1 = *(const float4*)(feat + (size_t)row * 32 + lq * 8 + 4);
            av[0] = (_Float16)v0.x; av[1] = (_Float16)v0.y;
            av[2] = (_Float16)v0.z; av[3] = (_Float16)v0.w;
            av[4] = (_Float16)v1.x; av[5] = (_Float16)v1.y;
            av[6] = (_Float16)v1.z; av[7] = (_Float16)v1.w;
        } else {
            #pragma unroll
            for (int j = 0; j < 8; j++) av[j] = (_Float16)0.f;
        }
        a[mi] = av;
    }
    #pragma unroll
    for (int ni = 0; ni < 2; ni++) {
        int col = wid * 32 + ni * 16 + lm;
        b[ni] = *(const f16x8*)&Bl[col * 32 + lq * 8];
    }
    #pragma unroll
    for (int mi = 0; mi < 4; mi++)
        #pragma unroll
        for (int ni = 0; ni < 2; ni++)
            acc[mi][ni] = __builtin_amdgcn_mfma_f32_16x16x32_f16(a[mi], b[ni], acc[mi][ni], 0, 0, 0);
    #pragma unroll
    for (int mi = 0; mi < 4; mi++)
        #pragma unroll
        for (int ni = 0; ni < 2; ni++) {
            int col = wid * 32 + ni * 16 + lm;
            float bc = bias[col];
            #pragma unroll
            for (int r = 0; r < 4; r++) {
                int rl = mi * 16 + lq * 4 + r;
                int row = m0 + rl;
                float v = acc[mi][ni][r] + bc;
                stg[rl * STL + col] = (_Float16)v;
                if (row < NN) h16[(size_t)row * 128 + col] = (_Float16)v;
            }
        }
    __syncthreads();
    // fused mm1 for layer 0 -> slice-major hp16
    floatx4 pacc[4][2];
    #pragma unroll
    for (int mi = 0; mi < 4; mi++)
        #pragma unroll
        for (int ni = 0; ni < 2; ni++) { floatx4 z = {0.f,0.f,0.f,0.f}; pacc[mi][ni] = z; }
    #pragma unroll
    for (int ks = 0; ks < 4; ks++) {
        f16x8 pa[4], pb[2];
        #pragma unroll
        for (int mi = 0; mi < 4; mi++)
            pa[mi] = *(const f16x8*)&stg[(mi * 16 + lm) * STL + ks * 32 + lq * 8];
        #pragma unroll
        for (int ni = 0; ni < 2; ni++)
            pb[ni] = *(const f16x8*)(Bt1n + (size_t)(wid * 32 + ni * 16 + lm) * 128 + ks * 32 + lq * 8);
        #pragma unroll
        for (int mi = 0; mi < 4; mi++)
            #pragma unroll
            for (int ni = 0; ni < 2; ni++)
                pacc[mi][ni] = __builtin_amdgcn_mfma_f32_16x16x32_f16(pa[mi], pb[ni], pacc[mi][ni], 0, 0, 0);
    }
    #pragma unroll
    for (int mi = 0; mi < 4; mi++)
        #pragma unroll
        for (int ni = 0; ni < 2; ni++) {
            int col = wid * 32 + ni * 16 + lm;
            float bc = bbPn[col];
            #pragma unroll
            for (int r = 0; r < 4; r++) {
                int row = m0 + mi * 16 + lq * 4 + r;
                if (row < NN)
                    hp16[((size_t)wid * NN + row) * 32 + ni * 16 + lm] =
                        (_Float16)fmaxf(pacc[mi][ni][r] + bc, 0.f);
            }
        }
}

// XCD-pinned column-sliced aggregation v7: 2-way edge-split + pair-unrolled
// gather (8 loads in flight per round; typical deg=16 node -> ONE memory round
// per split instead of two).
__global__ __launch_bounds__(256)
void k_agg3(const _Float16* __restrict__ hp16, const int* __restrict__ rp,
            const unsigned short* __restrict__ cs, _Float16* __restrict__ agg16) {
    int bid = blockIdx.x;
    int bkt = bid >> 2;
    int slice = bid & 3;
    int tid = threadIdx.x;
    int wv = tid >> 6, lane = tid & 63;
    int split = lane >> 5;           // 0 or 1
    int l5 = lane & 31;
    int nsub = l5 >> 2, c = l5 & 3;  // 8 nodes x 4 chunks per 32-lane half
    int n = bkt * 32 + wv * 8 + nsub;
    if (n < NN) {
        int s0 = rp[n], s1 = rp[n + 1];
        float acc[8];
        #pragma unroll
        for (int j = 0; j < 8; j++) acc[j] = 0.f;
        const _Float16* hb = hp16 + (size_t)slice * NN * 32 + c * 8;
        int e = s0 + split * 4;
        // paired rounds: this split's groups are 8 apart; issue two (8 gathers)
        for (; e + 12 <= s1; e += 16) {
            int ra[8];
            #pragma unroll
            for (int u = 0; u < 4; u++) ra[u] = __builtin_nontemporal_load(cs + e + u);
            #pragma unroll
            for (int u = 0; u < 4; u++) ra[4 + u] = __builtin_nontemporal_load(cs + e + 8 + u);
            f16x8 v[8];
            #pragma unroll
            for (int u = 0; u < 8; u++) v[u] = *(const f16x8*)(hb + (size_t)ra[u] * 32);
            #pragma unroll
            for (int j = 0; j < 8; j++)
                acc[j] += (((float)v[0][j] + (float)v[1][j]) + ((float)v[2][j] + (float)v[3][j]))
                        + (((float)v[4][j] + (float)v[5][j]) + ((float)v[6][j] + (float)v[7][j]));
        }
        for (; e + 4 <= s1; e += 8) {
            int r0 = __builtin_nontemporal_load(cs + e);
            int r1 = __builtin_nontemporal_load(cs + e + 1);
            int r2 = __builtin_nontemporal_load(cs + e + 2);
            int r3 = __builtin_nontemporal_load(cs + e + 3);
            f16x8 v0 = *(const f16x8*)(hb + (size_t)r0 * 32);
            f16x8 v1 = *(const f16x8*)(hb + (size_t)r1 * 32);
            f16x8 v2 = *(const f16x8*)(hb + (size_t)r2 * 32);
            f16x8 v3 = *(const f16x8*)(hb + (size_t)r3 * 32);
            #pragma unroll
            for (int j = 0; j < 8; j++)
                acc[j] += ((float)v0[j] + (float)v1[j]) + ((float)v2[j] + (float)v3[j]);
        }
        for (int t = e; t < s1 && t < e + 4; t++) {
            int r0 = __builtin_nontemporal_load(cs + t);
            f16x8 v0 = *(const f16x8*)(hb + (size_t)r0 * 32);
            #pragma unroll
            for (int j = 0; j < 8; j++) acc[j] += (float)v0[j];
        }
        #pragma unroll
        for (int j = 0; j < 8; j++) acc[j] += __shfl_xor(acc[j], 32, 64);
        if (split == 0) {
            int dg = s1 - s0;
            float inv = 1.0f / (float)((dg > 1) ? dg : 1);
            f16x8 o;
            #pragma unroll
            for (int j = 0; j < 8; j++) o[j] = (_Float16)(acc[j] * inv);
            uintx4 ov = *(uintx4*)&o;
            __builtin_nontemporal_store(ov, (uintx4*)(agg16 + (size_t)n * 128 + slice * 32 + c * 8));
        }
    }
}

// app MFMA (K=256) + l2norm + relu + residual, fused with next layer's mm1.
// v10: v9 LDS-staged A + B/bias prefetch BEFORE the staging barrier (compiler
// can't sink loads across __syncthreads) -> B L2 latency hides under the
// single staging HBM round. launch_bounds(256,4) for the ~110 VGPR this needs.
__global__ __launch_bounds__(256, 4)
void k_appmm1(const _Float16* __restrict__ Ah, const _Float16* __restrict__ Ag,
              const _Float16* __restrict__ Bt, const float* __restrict__ bias,
              const _Float16* __restrict__ Bt1n, const float* __restrict__ bbPn,
              float* __restrict__ h, _Float16* __restrict__ h16,
              _Float16* __restrict__ hp16, int do_mm1) {
    __shared__ float ssl[32 * 4];
    __shared__ float scl[32];
    __shared__ _Float16 lsbuf[2 * 32 * STL];   // [h16 tile | agg16 tile]; tile0 reused as stg
    _Float16* lA0 = lsbuf;
    _Float16* lA1 = lsbuf + 32 * STL;
    _Float16* stg = lsbuf;                      // alias (safe: 2 barriers between uses)
    int tid = threadIdx.x;
    int lane = tid & 63, wid = tid >> 6, lm = lane & 15, lq = lane >> 4;
    int m0 = blockIdx.x * 32;
    int colv[2], colc[2], cval[2];
    #pragma unroll
    for (int ni = 0; ni < 2; ni++) {
        int col = wid * 32 + ni * 16 + lm;
        colv[ni] = col;
        cval[ni] = (col < HID);
        colc[ni] = cval[ni] ? col : 0;   // clamp B row for masked cols
    }
    // ---- prefetch B fragments + bias (independent of LDS; issued pre-barrier) ----
    f16x8 bf[8][2];
    #pragma unroll
    for (int ks = 0; ks < 8; ks++)
        #pragma unroll
        for (int ni = 0; ni < 2; ni++)
            bf[ks][ni] = *(const f16x8*)(Bt + (size_t)colc[ni] * 256 + ks * 32 + lq * 8);
    float bc0 = bias[colv[0]];
    float bc1 = bias[colv[1]];
    // ---- stage A tiles: 1024 chunks of 16B, 4 per thread, all independent ----
    f16x8 sv[4];
    #pragma unroll
    for (int i = 0; i < 4; i++) {
        int id = tid + 256 * i;              // 0..1023
        int t = id >> 9;                      // tile: 0=h16, 1=agg16
        int rr = (id >> 4) & 31;              // row 0..31
        int cb = id & 15;                     // 16B chunk
        const _Float16* Asrc = t ? Ag : Ah;
        int grow = m0 + rr;
        if (grow >= NN) grow = 0;             // clamp: garbage only affects invalid rows
        sv[i] = *(const f16x8*)(Asrc + (size_t)grow * 128 + cb * 8);
    }
    #pragma unroll
    for (int i = 0; i < 4; i++) {
        int id = tid + 256 * i;
        int t = id >> 9;
        int rr = (id >> 4) & 31;
        int cb = id & 15;
        *(f16x8*)&lsbuf[(size_t)t * 32 * STL + rr * STL + cb * 8] = sv[i];
    }
    __syncthreads();
    floatx4 acc[2][2];
    #pragma unroll
    for (int mi = 0; mi < 2; mi++)
        #pragma unroll
        for (int ni = 0; ni < 2; ni++) { floatx4 z = {0.f,0.f,0.f,0.f}; acc[mi][ni] = z; }
    #pragma unroll
    for (int ks = 0; ks < 8; ks++) {
        const _Float16* lsrc = (ks < 4) ? lA0 : lA1;
        int ko = (ks & 3) * 32 + lq * 8;
        f16x8 a[2];
        #pragma unroll
        for (int mi = 0; mi < 2; mi++)
            a[mi] = *(const f16x8*)&lsrc[(mi * 16 + lm) * STL + ko];
        #pragma unroll
        for (int mi = 0; mi < 2; mi++)
            #pragma unroll
            for (int ni = 0; ni < 2; ni++)
                acc[mi][ni] = __builtin_amdgcn_mfma_f32_16x16x32_f16(a[mi], bf[ks][ni], acc[mi][ni], 0, 0, 0);
    }
    // residual base from the LDS h16 tile (no global round-trip)
    float hres[2][2][4];
    #pragma unroll
    for (int mi = 0; mi < 2; mi++)
        #pragma unroll
        for (int ni = 0; ni < 2; ni++)
            #pragma unroll
            for (int r = 0; r < 4; r++) {
                int rl = mi * 16 + lq * 4 + r;
                hres[mi][ni][r] = cval[ni] ? (float)lA0[rl * STL + colv[ni]] : 0.f;
            }
    // bias + masked sum of squares
    float ss[2][4];
    #pragma unroll
    for (int mi = 0; mi < 2; mi++)
        #pragma unroll
        for (int r = 0; r < 4; r++) {
            acc[mi][0][r] += bc0;
            acc[mi][1][r] += bc1;
            float c0 = cval[0] ? acc[mi][0][r] : 0.f;
            float c1 = cval[1] ? acc[mi][1][r] : 0.f;
            ss[mi][r] = c0 * c0 + c1 * c1;
        }
    #pragma unroll
    for (int off = 1; off < 16; off <<= 1)
        #pragma unroll
        for (int mi = 0; mi < 2; mi++)
            #pragma unroll
            for (int r = 0; r < 4; r++)
                ss[mi][r] += __shfl_xor(ss[mi][r], off, 64);
    if (lm == 0) {
        #pragma unroll
        for (int mi = 0; mi < 2; mi++)
            #pragma unroll
            for (int r = 0; r < 4; r++)
                ssl[(mi * 16 + lq * 4 + r) * 4 + wid] = ss[mi][r];
    }
    __syncthreads();
    if (tid < 32) {
        float s = ssl[tid * 4] + ssl[tid * 4 + 1] + ssl[tid * 4 + 2] + ssl[tid * 4 + 3];
        scl[tid] = 1.0f / fmaxf(sqrtf(s), 1e-12f);
    }
    __syncthreads();
    #pragma unroll
    for (int mi = 0; mi < 2; mi++)
        #pragma unroll
        for (int ni = 0; ni < 2; ni++) {
            int col = colv[ni];
            #pragma unroll
            for (int r = 0; r < 4; r++) {
                int rl = mi * 16 + lq * 4 + r;
                int row = m0 + rl;
                float hn = 0.f;
                if (cval[ni] && row < NN) {
                    float v = fmaxf(acc[mi][ni][r] * scl[rl], 0.f);
                    hn = hres[mi][ni][r] + v;
                    if (!do_mm1) h[(size_t)row * HID + col] = hn;   // last layer only
                    h16[(size_t)row * 128 + col] = (_Float16)hn;
                }
                stg[rl * STL + col] = (_Float16)hn;
            }
        }
    if (do_mm1) {
        __syncthreads();
        floatx4 pacc[2][2];
        #pragma unroll
        for (int mi = 0; mi < 2; mi++)
            #pragma unroll
            for (int ni = 0; ni < 2; ni++) { floatx4 z = {0.f,0.f,0.f,0.f}; pacc[mi][ni] = z; }
        #pragma unroll
        for (int ks = 0; ks < 4; ks++) {
            f16x8 pa[2], pb[2];
            #pragma unroll
            for (int mi = 0; mi < 2; mi++)
                pa[mi] = *(const f16x8*)&stg[(mi * 16 + lm) * STL + ks * 32 + lq * 8];
            #pragma unroll
            for (int ni = 0; ni < 2; ni++)
                pb[ni] = *(const f16x8*)(Bt1n + (size_t)colv[ni] * 128 + ks * 32 + lq * 8);
            #pragma unroll
            for (int mi = 0; mi < 2; mi++)
                #pragma unroll
                for (int ni = 0; ni < 2; ni++)
                    pacc[mi][ni] = __builtin_amdgcn_mfma_f32_16x16x32_f16(pa[mi], pb[ni], pacc[mi][ni], 0, 0, 0);
        }
        #pragma unroll
        for (int mi = 0; mi < 2; mi++)
            #pragma unroll
            for (int ni = 0; ni < 2; ni++) {
                float bc = bbPn[colv[ni]];
                #pragma unroll
                for (int r = 0; r < 4; r++) {
                    int row = m0 + mi * 16 + lq * 4 + r;
                    if (row < NN)
                        hp16[((size_t)wid * NN + row) * 32 + ni * 16 + lm] =
                            (_Float16)fmaxf(pacc[mi][ni][r] + bc, 0.f);
                }
            }
    }
}

// readout phase 1: per-(graph, slice) partial column sums of h
__global__ __launch_bounds__(128)
void k_seg(const float* __restrict__ h, const int* __restrict__ gid,
           float* __restrict__ hgp) {
    __shared__ int se[2];
    int g = blockIdx.x, sl = blockIdx.y, tid = threadIdx.x;
    if (tid < 2) {
        int key = g + tid, lo = 0, hi = NN;
        while (lo < hi) {
            int mid = (lo + hi) >> 1;
            if (gid[mid] < key) lo = mid + 1; else hi = mid;
        }
        se[tid] = lo;
    }
    __syncthreads();
    int s = se[0], e = se[1];
    int cnt = e - s;
    int chunk = (cnt + RS - 1) / RS;
    int ls = s + sl * chunk;
    int le = min(e, ls + chunk);
    if (tid < HID) {
        float acc = 0.f;
        for (int n = ls; n < le; n++) acc += h[(size_t)n * HID + tid];
        hgp[((size_t)g * RS + sl) * HID + tid] = acc;
    }
}

// readout phase 2: combine partials, mean, 3-layer MLP
__global__ __launch_bounds__(128)
void k_mlp(const float* __restrict__ hgp, const int* __restrict__ gid,
           const float* __restrict__ W1, const float* __restrict__ b1,
           const float* __restrict__ W2, const float* __restrict__ b2,
           const float* __restrict__ W3, const float* __restrict__ b3,
           float* __restrict__ out) {
    __shared__ float hg[HID];
    __shared__ float y1[54];
    __shared__ float y2[27];
    __shared__ int se[2];
    int g = blockIdx.x, tid = threadIdx.x;
    if (tid < 2) {
        int key = g + tid, lo = 0, hi = NN;
        while (lo < hi) {
            int mid = (lo + hi) >> 1;
            if (gid[mid] < key) lo = mid + 1; else hi = mid;
        }
        se[tid] = lo;
    }
    __syncthreads();
    int cnt = se[1] - se[0];
    if (tid < HID) {
        float acc = 0.f;
        #pragma unroll
        for (int sl = 0; sl < RS; sl++) acc += hgp[((size_t)g * RS + sl) * HID + tid];
        hg[tid] = acc / (float)((cnt > 1) ? cnt : 1);
    }
    __syncthreads();
    if (tid < 54) {
        float a = b1[tid];
        for (int k = 0; k < HID; k++) a += hg[k] * W1[k * 54 + tid];
        y1[tid] = fmaxf(a, 0.f);
    }
    __syncthreads();
    if (tid < 27) {
        float a = b2[tid];
        for (int k = 0; k < 54; k++) a += y1[k] * W2[k * 27 + tid];
        y2[tid] = fmaxf(a, 0.f);
    }
    __syncthreads();
    if (tid < 10) {
        float a = b3[tid];
        for (int k = 0; k < 27; k++) a += y2[k] * W3[k * 10 + tid];
        out[g * 10 + tid] = a;
    }
}

extern "C" void kernel_launch(void* const* d_in, const int* in_sizes, int n_in,
                              void* d_out, int out_size, void* d_ws, size_t ws_size,
                              hipStream_t stream) {
    float* out = (float*)d_out;
    (void)in_sizes; (void)n_in; (void)ws_size; (void)out_size;

    const float* feat   = (const float*)d_in[0];
    const int*   src    = (const int*)d_in[4];
    const int*   dst    = (const int*)d_in[5];
    const int*   gid    = (const int*)d_in[6];
    const float* W_emb  = (const float*)d_in[7];
    const float* b_emb  = (const float*)d_in[8];
    const float* W_pool = (const float*)d_in[9];
    const float* b_pool = (const float*)d_in[10];
    const float* W_app  = (const float*)d_in[11];
    const float* b_app  = (const float*)d_in[12];
    const float* W1     = (const float*)d_in[13];
    const float* b1     = (const float*)d_in[14];
    const float* W2     = (const float*)d_in[15];
    const float* b2     = (const float*)d_in[16];
    const float* W3     = (const float*)d_in[17];
    const float* b3     = (const float*)d_in[18];

    char* ws = (char*)d_ws;
    size_t off = 0;
    auto take = [&](size_t bytes) { char* p = ws + off; off += (bytes + 255) & ~(size_t)255; return p; };
    float*     h     = (float*)take((size_t)NN * HID * 4);
    _Float16*  h16   = (_Float16*)take((size_t)NN * 128 * 2);
    _Float16*  hp16  = (_Float16*)take((size_t)4 * NN * 32 * 2);   // slice-major [4][NN][32]
    _Float16*  agg16 = (_Float16*)take((size_t)NN * 128 * 2);
    unsigned short* cs = (unsigned short*)take((size_t)EE * 2);
    unsigned int* ebuf = (unsigned int*)take((size_t)SBN * SCAP * 4);
    int*       rp    = (int*)take((size_t)(NN + 1) * 4);
    int*       gfill = (int*)take((size_t)SBN * PAD * 4);
    float*     hgp   = (float*)take((size_t)GG * RS * HID * 4);
    _Float16*  Bt1   = (_Float16*)take((size_t)NL * 128 * 128 * 2);
    _Float16*  BtA   = (_Float16*)take((size_t)NL * 108 * 256 * 2);
    float*     bbP   = (float*)take((size_t)NL * 128 * 4);
    float*     bbA   = (float*)take((size_t)NL * 128 * 4);
    _Float16*  BtE   = (_Float16*)take((size_t)128 * 32 * 2);
    float*     bbE   = (float*)take((size_t)128 * 4);

    // ---- two-level coalesced CSR build ----
    hipLaunchKernelGGL(k_zero, dim3((SBN * PAD + 255) / 256), dim3(256), 0, stream,
                       gfill, SBN * PAD);
    hipLaunchKernelGGL(k_bin, dim3((EE + BCH - 1) / BCH), dim3(256), 0, stream,
                       src, dst, gfill, ebuf);
    hipLaunchKernelGGL(k_place2, dim3(SBN), dim3(256), 0, stream, ebuf, gfill, rp, cs);

    const int PACK_TOTAL = NL * 128 * 128 + NL * 108 * 256 + NL * 128 + NL * 128 + 128 * 32 + 128;
    hipLaunchKernelGGL(k_pack, dim3((PACK_TOTAL + 255) / 256), dim3(256), 0, stream,
                       W_pool, b_pool, W_app, b_app, W_emb, b_emb,
                       Bt1, BtA, bbP, bbA, BtE, bbE);

    hipLaunchKernelGGL(k_embed2, dim3(MB), dim3(256), 0, stream,
                       feat, BtE, bbE, Bt1, bbP, h16, hp16);

    for (int l = 0; l < NL; l++) {
        hipLaunchKernelGGL(k_agg3, dim3(4 * MB2), dim3(256), 0, stream,
                           hp16, rp, cs, agg16);
        int next = (l + 1 < NL) ? 1 : 0;
        hipLaunchKernelGGL(k_appmm1, dim3(MB2), dim3(256), 0, stream,
                           h16, agg16, BtA + (size_t)l * 108 * 256, bbA + (size_t)l * 128,
                           Bt1 + (size_t)(l + 1 < NL ? l + 1 : 0) * 128 * 128,
                           bbP + (size_t)(l + 1 < NL ? l + 1 : 0) * 128,
                           h, h16, hp16, next);
    }
    hipLaunchKernelGGL(k_seg, dim3(GG, RS), dim3(128), 0, stream, h, gid, hgp);
    hipLaunchKernelGGL(k_mlp, dim3(GG), dim3(128), 0, stream,
                       hgp, gid, W1, b1, W2, b2, W3, b3, out);
}

// Round 15
// 414.741 us; speedup vs baseline: 1.0414x; 1.0414x over previous
//
#include <hip/hip_runtime.h>

#define NN 50000
#define EE 800000
#define GG 256
#define IND 32
#define HID 108
#define NL 4
#define MB 782            // ceil(50000/64) M-tiles (embed)
#define MB2 1563          // ceil(50000/32) M-tiles (appmm1, agg)
#define RS 8              // readout slices per graph
#define SBN 196           // super-buckets of 256 nodes (ceil(50000/256))
#define SCAP 5120         // ebuf slot capacity per super-bucket (mean 4082, sd 64 -> 16 sigma)
#define PCAP 6144         // k_place2 LDS staging capacity
#define PAD 16            // ints (64B) padding for atomic counters
#define BCH 4096          // edges per k_bin block
#define STL 136           // LDS tile row stride (halves): 272B -> 2-way (free) bank aliasing

typedef __attribute__((ext_vector_type(8))) _Float16 f16x8;
typedef __attribute__((ext_vector_type(4))) float floatx4;
typedef __attribute__((ext_vector_type(4))) unsigned int uintx4;

__global__ void k_zero(int* p, int n) {
    int i = blockIdx.x * 256 + threadIdx.x;
    if (i < n) p[i] = 0;
}

// ---- two-level coalesced CSR build ----
// level 1: bin edges by super-bucket (dst>>8) with LDS staging so global writes
// are contiguous runs per (block, super-bucket). payload = (sb<<24)|(src<<8)|(dst&255)
__global__ __launch_bounds__(256)
void k_bin(const int* __restrict__ src, const int* __restrict__ dst,
           int* __restrict__ gfill, unsigned int* __restrict__ ebuf) {
    __shared__ unsigned int stage[BCH];
    __shared__ int scnt[SBN], soff[SBN], gres[SBN];
    int tid = threadIdx.x;
    int e0 = blockIdx.x * BCH;
    for (int i = tid; i < SBN; i += 256) scnt[i] = 0;
    __syncthreads();
    unsigned int pay[16]; int psb[16];
    #pragma unroll
    for (int j = 0; j < 16; j++) {
        int e = e0 + j * 256 + tid;              // coalesced
        if (e < EE) {
            int d = dst[e]; int s = src[e];
            int sb = d >> 8;
            psb[j] = sb;
            pay[j] = ((unsigned)sb << 24) | ((unsigned)s << 8) | (unsigned)(d & 255);
            atomicAdd(&scnt[sb], 1);
        } else psb[j] = -1;
    }
    __syncthreads();
    if (tid == 0) {
        int run = 0;
        for (int s = 0; s < SBN; s++) { soff[s] = run; run += scnt[s]; }
    }
    __syncthreads();
    if (tid < SBN) gres[tid] = atomicAdd(&gfill[tid * PAD], scnt[tid]);
    __syncthreads();
    if (tid < SBN) scnt[tid] = 0;
    __syncthreads();
    #pragma unroll
    for (int j = 0; j < 16; j++) {
        if (psb[j] >= 0) {
            int p = soff[psb[j]] + atomicAdd(&scnt[psb[j]], 1);
            stage[p] = pay[j];
        }
    }
    __syncthreads();
    int nv = soff[SBN - 1] + scnt[SBN - 1];
    for (int i = tid; i < nv; i += 256) {
        unsigned int v = stage[i];
        int sb = v >> 24;
        int idx = gres[sb] + (i - soff[sb]);
        if (idx < SCAP) ebuf[(size_t)sb * SCAP + idx] = v & 0xFFFFFFu;  // (src<<8)|loc
    }
}

// level 2: per super-bucket, build node-sorted CSR fully in LDS, coalesced writes.
// emits rp (256 nodes) and cs (ushort: src < 50000 < 2^16).
__global__ __launch_bounds__(256)
void k_place2(const unsigned int* __restrict__ ebuf, const int* __restrict__ gfill,
              int* __restrict__ rp, unsigned short* __restrict__ cs) {
    __shared__ int outb[PCAP];
    __shared__ int cnt[256];
    __shared__ int off[256];
    __shared__ int fl[SBN];
    __shared__ int sbase;
    __shared__ int wsum[4], wexc[4];
    int sb = blockIdx.x, tid = threadIdx.x;
    if (tid < SBN) fl[tid] = gfill[tid * PAD];
    cnt[tid] = 0;
    __syncthreads();
    if (tid == 0) {
        int run = 0;
        for (int s = 0; s < sb; s++) run += fl[s];
        sbase = run;
    }
    __syncthreads();
    int nE = fl[sb]; if (nE > SCAP) nE = SCAP;
    int base = sbase;
    const unsigned int* eb = ebuf + (size_t)sb * SCAP;
    for (int i = tid; i < nE; i += 256) atomicAdd(&cnt[eb[i] & 255], 1);
    __syncthreads();
    // exclusive scan of 256 counts
    int v = cnt[tid];
    int lane = tid & 63, wv = tid >> 6;
    int x = v;
    #pragma unroll
    for (int o = 1; o < 64; o <<= 1) {
        int y = __shfl_up(x, o, 64);
        if (lane >= o) x += y;
    }
    if (lane == 63) wsum[wv] = x;
    __syncthreads();
    if (tid == 0) { int run = 0; for (int w = 0; w < 4; w++) { wexc[w] = run; run += wsum[w]; } }
    __syncthreads();
    int myoff = wexc[wv] + x - v;
    off[tid] = myoff;
    int n = (sb << 8) + tid;
    if (n <= NN) rp[n] = base + myoff;
    cnt[tid] = 0;
    __syncthreads();
    if (nE <= PCAP) {
        for (int i = tid; i < nE; i += 256) {
            unsigned int e = eb[i];
            int loc = e & 255;
            int p = atomicAdd(&cnt[loc], 1);
            outb[off[loc] + p] = (int)(e >> 8);
        }
        __syncthreads();
        for (int i = tid; i < nE; i += 256) cs[base + i] = (unsigned short)outb[i];
    } else {
        for (int i = tid; i < nE; i += 256) {
            unsigned int e = eb[i];
            int loc = e & 255;
            int p = atomicAdd(&cnt[loc], 1);
            cs[base + off[loc] + p] = (unsigned short)(e >> 8);
        }
    }
}

// Pack weights (fp16, transposed, padded):
// Bt1[l][128][128]  : pool, n<108,k<108 -> W_pool[l][k][n]
// BtA[l][108][256]  : app,  row n<108; k<108 -> W_app[l][k][n]; 128<=k<236 -> W_app[l][108+k-128][n]
__global__ void k_pack(const float* __restrict__ W_pool, const float* __restrict__ b_pool,
                       const float* __restrict__ W_app, const float* __restrict__ b_app,
                       const float* __restrict__ W_emb, const float* __restrict__ b_emb,
                       _Float16* Bt1, _Float16* BtA, float* bbP, float* bbA,
                       _Float16* BtE, float* bbE) {
    int r = blockIdx.x * 256 + threadIdx.x;
    if (r < NL * 128 * 128) {
        int l = r / (128 * 128); int t = r % (128 * 128); int n = t / 128, k = t % 128;
        float v = (n < HID && k < HID) ? W_pool[((size_t)l * HID + k) * HID + n] : 0.f;
        Bt1[r] = (_Float16)v; return;
    } r -= NL * 128 * 128;
    if (r < NL * 108 * 256) {
        int l = r / (108 * 256); int t = r % (108 * 256); int n = t / 256, k = t % 256;
        float v = 0.f;
        if (k < HID)                        v = W_app[((size_t)l * 216 + k) * HID + n];
        else if (k >= 128 && k < 128 + HID) v = W_app[((size_t)l * 216 + 108 + (k - 128)) * HID + n];
        BtA[r] = (_Float16)v; return;
    } r -= NL * 108 * 256;
    if (r < NL * 128) { int l = r / 128, n = r % 128; bbP[r] = (n < HID) ? b_pool[l * HID + n] : 0.f; return; } r -= NL * 128;
    if (r < NL * 128) { int l = r / 128, n = r % 128; bbA[r] = (n < HID) ? b_app[l * HID + n] : 0.f; return; } r -= NL * 128;
    if (r < 128 * 32) {
        int n = r / 32, k = r % 32;
        BtE[r] = (n < HID) ? (_Float16)W_emb[k * HID + n] : (_Float16)0.f; return;
    } r -= 128 * 32;
    if (r < 128) { bbE[r] = (r < HID) ? b_emb[r] : 0.f; }
}

// embed via MFMA + fused mm1(layer 0):
// v = feat(fp16)[M,32] @ BtE^T + bias -> h16 (fp16 residual carrier); stage v in LDS;
// hp16 (slice-major [4][NN][32]) = relu(stage @ Bt1[0]^T + bbP[0])
__global__ __launch_bounds__(256)
void k_embed2(const float* __restrict__ feat, const _Float16* __restrict__ BtE,
              const float* __restrict__ bias,
              const _Float16* __restrict__ Bt1n, const float* __restrict__ bbPn,
              _Float16* __restrict__ h16, _Float16* __restrict__ hp16) {
    __shared__ _Float16 Bl[128 * 32];
    __shared__ _Float16 stg[64 * STL];
    int tid = threadIdx.x;
    for (int i = tid; i < 128 * 32 / 8; i += 256)
        ((uintx4*)Bl)[i] = ((const uintx4*)BtE)[i];
    __syncthreads();
    int lane = tid & 63, wid = tid >> 6, lm = lane & 15, lq = lane >> 4;
    int m0 = blockIdx.x * 64;
    floatx4 acc[4][2];
    #pragma unroll
    for (int mi = 0; mi < 4; mi++)
        #pragma unroll
        for (int ni = 0; ni < 2; ni++) { floatx4 z = {0.f,0.f,0.f,0.f}; acc[mi][ni] = z; }
    f16x8 a[4], b[2];
    #pragma unroll
    for (int mi = 0; mi < 4; mi++) {
        int row = m0 + mi * 16 + lm;
        f16x8 av;
        if (row < NN) {
            const float4 v0 = *(const float4*)(feat + (size_t)row * 32 + lq * 8);
            const float4 v1 = *(const float4*)(feat + (size_t)row * 32 + lq * 8 + 4);
            av[0] = (_Float16)v0.x; av[1] = (_Float16)v0.y;
            av[2] = (_Float16)v0.z; av[3] = (_Float16)v0.w;
            av[4] = (_Float16)v1.x; av[5] = (_Float16)v1.y;
            av[6] = (_Float16)v1.z; av[7] = (_Float16)v1.w;
        } else {
            #pragma unroll
            for (int j = 0; j < 8; j++) av[j] = (_Float16)0.f;
        }
        a[mi] = av;
    }
    #pragma unroll
    for (int ni = 0; ni < 2; ni++) {
        int col = wid * 32 + ni * 16 + lm;
        b[ni] = *(const f16x8*)&Bl[col * 32 + lq * 8];
    }
    #pragma unroll
    for (int mi = 0; mi < 4; mi++)
        #pragma unroll
        for (int ni = 0; ni < 2; ni++)
            acc[mi][ni] = __builtin_amdgcn_mfma_f32_16x16x32_f16(a[mi], b[ni], acc[mi][ni], 0, 0, 0);
    #pragma unroll
    for (int mi = 0; mi < 4; mi++)
        #pragma unroll
        for (int ni = 0; ni < 2; ni++) {
            int col = wid * 32 + ni * 16 + lm;
            float bc = bias[col];
            #pragma unroll
            for (int r = 0; r < 4; r++) {
                int rl = mi * 16 + lq * 4 + r;
                int row = m0 + rl;
                float v = acc[mi][ni][r] + bc;
                stg[rl * STL + col] = (_Float16)v;
                if (row < NN) h16[(size_t)row * 128 + col] = (_Float16)v;
            }
        }
    __syncthreads();
    // fused mm1 for layer 0 -> slice-major hp16
    floatx4 pacc[4][2];
    #pragma unroll
    for (int mi = 0; mi < 4; mi++)
        #pragma unroll
        for (int ni = 0; ni < 2; ni++) { floatx4 z = {0.f,0.f,0.f,0.f}; pacc[mi][ni] = z; }
    #pragma unroll
    for (int ks = 0; ks < 4; ks++) {
        f16x8 pa[4], pb[2];
        #pragma unroll
        for (int mi = 0; mi < 4; mi++)
            pa[mi] = *(const f16x8*)&stg[(mi * 16 + lm) * STL + ks * 32 + lq * 8];
        #pragma unroll
        for (int ni = 0; ni < 2; ni++)
            pb[ni] = *(const f16x8*)(Bt1n + (size_t)(wid * 32 + ni * 16 + lm) * 128 + ks * 32 + lq * 8);
        #pragma unroll
        for (int mi = 0; mi < 4; mi++)
            #pragma unroll
            for (int ni = 0; ni < 2; ni++)
                pacc[mi][ni] = __builtin_amdgcn_mfma_f32_16x16x32_f16(pa[mi], pb[ni], pacc[mi][ni], 0, 0, 0);
    }
    #pragma unroll
    for (int mi = 0; mi < 4; mi++)
        #pragma unroll
        for (int ni = 0; ni < 2; ni++) {
            int col = wid * 32 + ni * 16 + lm;
            float bc = bbPn[col];
            #pragma unroll
            for (int r = 0; r < 4; r++) {
                int row = m0 + mi * 16 + lq * 4 + r;
                if (row < NN)
                    hp16[((size_t)wid * NN + row) * 32 + ni * 16 + lm] =
                        (_Float16)fmaxf(pacc[mi][ni][r] + bc, 0.f);
            }
        }
}

// XCD-pinned column-sliced aggregation v6: 2-way edge-split per (node, chunk).
__global__ __launch_bounds__(256)
void k_agg3(const _Float16* __restrict__ hp16, const int* __restrict__ rp,
            const unsigned short* __restrict__ cs, _Float16* __restrict__ agg16) {
    int bid = blockIdx.x;
    int bkt = bid >> 2;
    int slice = bid & 3;
    int tid = threadIdx.x;
    int wv = tid >> 6, lane = tid & 63;
    int split = lane >> 5;           // 0 or 1
    int l5 = lane & 31;
    int nsub = l5 >> 2, c = l5 & 3;  // 8 nodes x 4 chunks per 32-lane half
    int n = bkt * 32 + wv * 8 + nsub;
    if (n < NN) {
        int s0 = rp[n], s1 = rp[n + 1];
        float acc[8];
        #pragma unroll
        for (int j = 0; j < 8; j++) acc[j] = 0.f;
        const _Float16* hb = hp16 + (size_t)slice * NN * 32 + c * 8;
        int e = s0 + split * 4;
        for (; e + 4 <= s1; e += 8) {
            int r0 = __builtin_nontemporal_load(cs + e);
            int r1 = __builtin_nontemporal_load(cs + e + 1);
            int r2 = __builtin_nontemporal_load(cs + e + 2);
            int r3 = __builtin_nontemporal_load(cs + e + 3);
            f16x8 v0 = *(const f16x8*)(hb + (size_t)r0 * 32);
            f16x8 v1 = *(const f16x8*)(hb + (size_t)r1 * 32);
            f16x8 v2 = *(const f16x8*)(hb + (size_t)r2 * 32);
            f16x8 v3 = *(const f16x8*)(hb + (size_t)r3 * 32);
            #pragma unroll
            for (int j = 0; j < 8; j++)
                acc[j] += ((float)v0[j] + (float)v1[j]) + ((float)v2[j] + (float)v3[j]);
        }
        for (int t = e; t < s1 && t < e + 4; t++) {
            int r0 = __builtin_nontemporal_load(cs + t);
            f16x8 v0 = *(const f16x8*)(hb + (size_t)r0 * 32);
            #pragma unroll
            for (int j = 0; j < 8; j++) acc[j] += (float)v0[j];
        }
        #pragma unroll
        for (int j = 0; j < 8; j++) acc[j] += __shfl_xor(acc[j], 32, 64);
        if (split == 0) {
            int dg = s1 - s0;
            float inv = 1.0f / (float)((dg > 1) ? dg : 1);
            f16x8 o;
            #pragma unroll
            for (int j = 0; j < 8; j++) o[j] = (_Float16)(acc[j] * inv);
            uintx4 ov = *(uintx4*)&o;
            __builtin_nontemporal_store(ov, (uintx4*)(agg16 + (size_t)n * 128 + slice * 32 + c * 8));
        }
    }
}

// app MFMA (K=256) + l2norm + relu + residual, fused with next layer's mm1.
// v9 (R12-proven): LDS-staged A-operands. Each thread issues 4 INDEPENDENT 16B
// loads (block's 32x128 h16 + agg16 tiles), ds_write to padded LDS, barrier;
// K-loop + residual read LDS (~12cy) instead of serialized HBM (~900cy).
// Only B-fragment loads stay global (BtA 55KB -> L1/L2-resident).
// stg aliases tile0 (two barriers separate last read from first write).
__global__ __launch_bounds__(256, 6)
void k_appmm1(const _Float16* __restrict__ Ah, const _Float16* __restrict__ Ag,
              const _Float16* __restrict__ Bt, const float* __restrict__ bias,
              const _Float16* __restrict__ Bt1n, const float* __restrict__ bbPn,
              float* __restrict__ h, _Float16* __restrict__ h16,
              _Float16* __restrict__ hp16, int do_mm1) {
    __shared__ float ssl[32 * 4];
    __shared__ float scl[32];
    __shared__ _Float16 lsbuf[2 * 32 * STL];   // [h16 tile | agg16 tile]; tile0 reused as stg
    _Float16* lA0 = lsbuf;
    _Float16* lA1 = lsbuf + 32 * STL;
    _Float16* stg = lsbuf;                      // alias (safe: 2 barriers between uses)
    int tid = threadIdx.x;
    int lane = tid & 63, wid = tid >> 6, lm = lane & 15, lq = lane >> 4;
    int m0 = blockIdx.x * 32;
    // ---- stage A tiles: 1024 chunks of 16B, 4 per thread, all independent ----
    f16x8 sv[4];
    #pragma unroll
    for (int i = 0; i < 4; i++) {
        int id = tid + 256 * i;              // 0..1023
        int t = id >> 9;                      // tile: 0=h16, 1=agg16
        int rr = (id >> 4) & 31;              // row 0..31
        int cb = id & 15;                     // 16B chunk
        const _Float16* Asrc = t ? Ag : Ah;
        int grow = m0 + rr;
        if (grow >= NN) grow = 0;             // clamp: garbage only affects invalid rows
        sv[i] = *(const f16x8*)(Asrc + (size_t)grow * 128 + cb * 8);
    }
    #pragma unroll
    for (int i = 0; i < 4; i++) {
        int id = tid + 256 * i;
        int t = id >> 9;
        int rr = (id >> 4) & 31;
        int cb = id & 15;
        *(f16x8*)&lsbuf[(size_t)t * 32 * STL + rr * STL + cb * 8] = sv[i];
    }
    __syncthreads();
    int colv[2], colc[2], cval[2];
    #pragma unroll
    for (int ni = 0; ni < 2; ni++) {
        int col = wid * 32 + ni * 16 + lm;
        colv[ni] = col;
        cval[ni] = (col < HID);
        colc[ni] = cval[ni] ? col : 0;   // clamp B row for masked cols
    }
    floatx4 acc[2][2];
    #pragma unroll
    for (int mi = 0; mi < 2; mi++)
        #pragma unroll
        for (int ni = 0; ni < 2; ni++) { floatx4 z = {0.f,0.f,0.f,0.f}; acc[mi][ni] = z; }
    #pragma unroll
    for (int ks = 0; ks < 8; ks++) {
        const _Float16* lsrc = (ks < 4) ? lA0 : lA1;
        int ko = (ks & 3) * 32 + lq * 8;
        f16x8 a[2], b[2];
        #pragma unroll
        for (int mi = 0; mi < 2; mi++)
            a[mi] = *(const f16x8*)&lsrc[(mi * 16 + lm) * STL + ko];
        #pragma unroll
        for (int ni = 0; ni < 2; ni++)
            b[ni] = *(const f16x8*)(Bt + (size_t)colc[ni] * 256 + ks * 32 + lq * 8);
        #pragma unroll
        for (int mi = 0; mi < 2; mi++)
            #pragma unroll
            for (int ni = 0; ni < 2; ni++)
                acc[mi][ni] = __builtin_amdgcn_mfma_f32_16x16x32_f16(a[mi], b[ni], acc[mi][ni], 0, 0, 0);
    }
    // residual base from the LDS h16 tile (no global round-trip)
    float hres[2][2][4];
    #pragma unroll
    for (int mi = 0; mi < 2; mi++)
        #pragma unroll
        for (int ni = 0; ni < 2; ni++)
            #pragma unroll
            for (int r = 0; r < 4; r++) {
                int rl = mi * 16 + lq * 4 + r;
                hres[mi][ni][r] = cval[ni] ? (float)lA0[rl * STL + colv[ni]] : 0.f;
            }
    // bias + masked sum of squares
    float ss[2][4];
    #pragma unroll
    for (int mi = 0; mi < 2; mi++)
        #pragma unroll
        for (int r = 0; r < 4; r++) {
            float bc0 = bias[colv[0]];
            float bc1 = bias[colv[1]];
            acc[mi][0][r] += bc0;
            acc[mi][1][r] += bc1;
            float c0 = cval[0] ? acc[mi][0][r] : 0.f;
            float c1 = cval[1] ? acc[mi][1][r] : 0.f;
            ss[mi][r] = c0 * c0 + c1 * c1;
        }
    #pragma unroll
    for (int off = 1; off < 16; off <<= 1)
        #pragma unroll
        for (int mi = 0; mi < 2; mi++)
            #pragma unroll
            for (int r = 0; r < 4; r++)
                ss[mi][r] += __shfl_xor(ss[mi][r], off, 64);
    if (lm == 0) {
        #pragma unroll
        for (int mi = 0; mi < 2; mi++)
            #pragma unroll
            for (int r = 0; r < 4; r++)
                ssl[(mi * 16 + lq * 4 + r) * 4 + wid] = ss[mi][r];
    }
    __syncthreads();
    if (tid < 32) {
        float s = ssl[tid * 4] + ssl[tid * 4 + 1] + ssl[tid * 4 + 2] + ssl[tid * 4 + 3];
        scl[tid] = 1.0f / fmaxf(sqrtf(s), 1e-12f);
    }
    __syncthreads();
    #pragma unroll
    for (int mi = 0; mi < 2; mi++)
        #pragma unroll
        for (int ni = 0; ni < 2; ni++) {
            int col = colv[ni];
            #pragma unroll
            for (int r = 0; r < 4; r++) {
                int rl = mi * 16 + lq * 4 + r;
                int row = m0 + rl;
                float hn = 0.f;
                if (cval[ni] && row < NN) {
                    float v = fmaxf(acc[mi][ni][r] * scl[rl], 0.f);
                    hn = hres[mi][ni][r] + v;
                    if (!do_mm1) h[(size_t)row * HID + col] = hn;   // last layer only
                    h16[(size_t)row * 128 + col] = (_Float16)hn;
                }
                stg[rl * STL + col] = (_Float16)hn;
            }
        }
    if (do_mm1) {
        __syncthreads();
        floatx4 pacc[2][2];
        #pragma unroll
        for (int mi = 0; mi < 2; mi++)
            #pragma unroll
            for (int ni = 0; ni < 2; ni++) { floatx4 z = {0.f,0.f,0.f,0.f}; pacc[mi][ni] = z; }
        #pragma unroll
        for (int ks = 0; ks < 4; ks++) {
            f16x8 pa[2], pb[2];
            #pragma unroll
            for (int mi = 0; mi < 2; mi++)
                pa[mi] = *(const f16x8*)&stg[(mi * 16 + lm) * STL + ks * 32 + lq * 8];
            #pragma unroll
            for (int ni = 0; ni < 2; ni++)
                pb[ni] = *(const f16x8*)(Bt1n + (size_t)colv[ni] * 128 + ks * 32 + lq * 8);
            #pragma unroll
            for (int mi = 0; mi < 2; mi++)
                #pragma unroll
                for (int ni = 0; ni < 2; ni++)
                    pacc[mi][ni] = __builtin_amdgcn_mfma_f32_16x16x32_f16(pa[mi], pb[ni], pacc[mi][ni], 0, 0, 0);
        }
        #pragma unroll
        for (int mi = 0; mi < 2; mi++)
            #pragma unroll
            for (int ni = 0; ni < 2; ni++) {
                float bc = bbPn[colv[ni]];
                #pragma unroll
                for (int r = 0; r < 4; r++) {
                    int row = m0 + mi * 16 + lq * 4 + r;
                    if (row < NN)
                        hp16[((size_t)wid * NN + row) * 32 + ni * 16 + lm] =
                            (_Float16)fmaxf(pacc[mi][ni][r] + bc, 0.f);
                }
            }
    }
}

// readout phase 1: per-(graph, slice) partial column sums of h
__global__ __launch_bounds__(128)
void k_seg(const float* __restrict__ h, const int* __restrict__ gid,
           float* __restrict__ hgp) {
    __shared__ int se[2];
    int g = blockIdx.x, sl = blockIdx.y, tid = threadIdx.x;
    if (tid < 2) {
        int key = g + tid, lo = 0, hi = NN;
        while (lo < hi) {
            int mid = (lo + hi) >> 1;
            if (gid[mid] < key) lo = mid + 1; else hi = mid;
        }
        se[tid] = lo;
    }
    __syncthreads();
    int s = se[0], e = se[1];
    int cnt = e - s;
    int chunk = (cnt + RS - 1) / RS;
    int ls = s + sl * chunk;
    int le = min(e, ls + chunk);
    if (tid < HID) {
        float acc = 0.f;
        for (int n = ls; n < le; n++) acc += h[(size_t)n * HID + tid];
        hgp[((size_t)g * RS + sl) * HID + tid] = acc;
    }
}

// readout phase 2: combine partials, mean, 3-layer MLP
__global__ __launch_bounds__(128)
void k_mlp(const float* __restrict__ hgp, const int* __restrict__ gid,
           const float* __restrict__ W1, const float* __restrict__ b1,
           const float* __restrict__ W2, const float* __restrict__ b2,
           const float* __restrict__ W3, const float* __restrict__ b3,
           float* __restrict__ out) {
    __shared__ float hg[HID];
    __shared__ float y1[54];
    __shared__ float y2[27];
    __shared__ int se[2];
    int g = blockIdx.x, tid = threadIdx.x;
    if (tid < 2) {
        int key = g + tid, lo = 0, hi = NN;
        while (lo < hi) {
            int mid = (lo + hi) >> 1;
            if (gid[mid] < key) lo = mid + 1; else hi = mid;
        }
        se[tid] = lo;
    }
    __syncthreads();
    int cnt = se[1] - se[0];
    if (tid < HID) {
        float acc = 0.f;
        #pragma unroll
        for (int sl = 0; sl < RS; sl++) acc += hgp[((size_t)g * RS + sl) * HID + tid];
        hg[tid] = acc / (float)((cnt > 1) ? cnt : 1);
    }
    __syncthreads();
    if (tid < 54) {
        float a = b1[tid];
        for (int k = 0; k < HID; k++) a += hg[k] * W1[k * 54 + tid];
        y1[tid] = fmaxf(a, 0.f);
    }
    __syncthreads();
    if (tid < 27) {
        float a = b2[tid];
        for (int k = 0; k < 54; k++) a += y1[k] * W2[k * 27 + tid];
        y2[tid] = fmaxf(a, 0.f);
    }
    __syncthreads();
    if (tid < 10) {
        float a = b3[tid];
        for (int k = 0; k < 27; k++) a += y2[k] * W3[k * 10 + tid];
        out[g * 10 + tid] = a;
    }
}

extern "C" void kernel_launch(void* const* d_in, const int* in_sizes, int n_in,
                              void* d_out, int out_size, void* d_ws, size_t ws_size,
                              hipStream_t stream) {
    float* out = (float*)d_out;
    (void)in_sizes; (void)n_in; (void)ws_size; (void)out_size;

    const float* feat   = (const float*)d_in[0];
    const int*   src    = (const int*)d_in[4];
    const int*   dst    = (const int*)d_in[5];
    const int*   gid    = (const int*)d_in[6];
    const float* W_emb  = (const float*)d_in[7];
    const float* b_emb  = (const float*)d_in[8];
    const float* W_pool = (const float*)d_in[9];
    const float* b_pool = (const float*)d_in[10];
    const float* W_app  = (const float*)d_in[11];
    const float* b_app  = (const float*)d_in[12];
    const float* W1     = (const float*)d_in[13];
    const float* b1     = (const float*)d_in[14];
    const float* W2     = (const float*)d_in[15];
    const float* b2     = (const float*)d_in[16];
    const float* W3     = (const float*)d_in[17];
    const float* b3     = (const float*)d_in[18];

    char* ws = (char*)d_ws;
    size_t off = 0;
    auto take = [&](size_t bytes) { char* p = ws + off; off += (bytes + 255) & ~(size_t)255; return p; };
    float*     h     = (float*)take((size_t)NN * HID * 4);
    _Float16*  h16   = (_Float16*)take((size_t)NN * 128 * 2);
    _Float16*  hp16  = (_Float16*)take((size_t)4 * NN * 32 * 2);   // slice-major [4][NN][32]
    _Float16*  agg16 = (_Float16*)take((size_t)NN * 128 * 2);
    unsigned short* cs = (unsigned short*)take((size_t)EE * 2);
    unsigned int* ebuf = (unsigned int*)take((size_t)SBN * SCAP * 4);
    int*       rp    = (int*)take((size_t)(NN + 1) * 4);
    int*       gfill = (int*)take((size_t)SBN * PAD * 4);
    float*     hgp   = (float*)take((size_t)GG * RS * HID * 4);
    _Float16*  Bt1   = (_Float16*)take((size_t)NL * 128 * 128 * 2);
    _Float16*  BtA   = (_Float16*)take((size_t)NL * 108 * 256 * 2);
    float*     bbP   = (float*)take((size_t)NL * 128 * 4);
    float*     bbA   = (float*)take((size_t)NL * 128 * 4);
    _Float16*  BtE   = (_Float16*)take((size_t)128 * 32 * 2);
    float*     bbE   = (float*)take((size_t)128 * 4);

    // ---- two-level coalesced CSR build ----
    hipLaunchKernelGGL(k_zero, dim3((SBN * PAD + 255) / 256), dim3(256), 0, stream,
                       gfill, SBN * PAD);
    hipLaunchKernelGGL(k_bin, dim3((EE + BCH - 1) / BCH), dim3(256), 0, stream,
                       src, dst, gfill, ebuf);
    hipLaunchKernelGGL(k_place2, dim3(SBN), dim3(256), 0, stream, ebuf, gfill, rp, cs);

    const int PACK_TOTAL = NL * 128 * 128 + NL * 108 * 256 + NL * 128 + NL * 128 + 128 * 32 + 128;
    hipLaunchKernelGGL(k_pack, dim3((PACK_TOTAL + 255) / 256), dim3(256), 0, stream,
                       W_pool, b_pool, W_app, b_app, W_emb, b_emb,
                       Bt1, BtA, bbP, bbA, BtE, bbE);

    hipLaunchKernelGGL(k_embed2, dim3(MB), dim3(256), 0, stream,
                       feat, BtE, bbE, Bt1, bbP, h16, hp16);

    for (int l = 0; l < NL; l++) {
        hipLaunchKernelGGL(k_agg3, dim3(4 * MB2), dim3(256), 0, stream,
                           hp16, rp, cs, agg16);
        int next = (l + 1 < NL) ? 1 : 0;
        hipLaunchKernelGGL(k_appmm1, dim3(MB2), dim3(256), 0, stream,
                           h16, agg16, BtA + (size_t)l * 108 * 256, bbA + (size_t)l * 128,
                           Bt1 + (size_t)(l + 1 < NL ? l + 1 : 0) * 128 * 128,
                           bbP + (size_t)(l + 1 < NL ? l + 1 : 0) * 128,
                           h, h16, hp16, next);
    }
    hipLaunchKernelGGL(k_seg, dim3(GG, RS), dim3(128), 0, stream, h, gid, hgp);
    hipLaunchKernelGGL(k_mlp, dim3(GG), dim3(128), 0, stream,
                       hgp, gid, W1, b1, W2, b2, W3, b3, out);
}